// Round 22
// baseline (139.808 us; speedup 1.0000x reference)
//
#include <hip/hip_runtime.h>
#include <math.h>

#define NROWS 32768
#define DDIM 256
#define KCODES 1024

typedef __attribute__((ext_vector_type(8))) short bf16x8;
typedef __attribute__((ext_vector_type(4))) float f32x4;
typedef __attribute__((ext_vector_type(4))) unsigned short u16x4;
typedef __attribute__((address_space(3))) unsigned int lds_uint;
typedef const __attribute__((address_space(1))) unsigned int glb_uint;

__device__ __forceinline__ unsigned short f2bf(float f) {
    unsigned int u;
    __builtin_memcpy(&u, &f, 4);
    u += 0x7fffu + ((u >> 16) & 1u);
    return (unsigned short)(u >> 16);
}

// Rigorous k*-survival margin (R17 derivation): >= 2*E + 2*dnp,
// E = 2*(2^-7*1.004 + 255*2^-24)*||x||*||e||max, ||e||max<=0.463,
// dnp <= 2.3e-4  =>  0.0146*sqrt(x2) + 4.6e-4. Field-tested R13-R21.
__device__ __forceinline__ float screen_margin(float x2v) {
    return 0.0147f * sqrtf(x2v) + 5e-4f;
}

// ---- x2 = np.sum(x*x,1) via numpy AVX512 pairwise tree (bit-exact, R6) -----
constexpr int X2ROWS = 32;
__global__ __launch_bounds__(256) void vq_x2xb(const float* __restrict__ x,
                                               float* __restrict__ x2,
                                               unsigned short* __restrict__ xb) {
    __shared__ float lds[X2ROWS][257];
    const int rb = blockIdx.x;
    const int tid = threadIdx.x;
    const float4* src =
        reinterpret_cast<const float4*>(x + (size_t)rb * X2ROWS * DDIM);
#pragma unroll
    for (int i = 0; i < 8; ++i) {
        int e4 = tid + i * 256;
        int row = e4 >> 6;
        int col = e4 & 63;
        float4 v = src[e4];
        lds[row][col * 4 + 0] = v.x;
        lds[row][col * 4 + 1] = v.y;
        lds[row][col * 4 + 2] = v.z;
        lds[row][col * 4 + 3] = v.w;
        u16x4 h;
        h.x = f2bf(v.x);
        h.y = f2bf(v.y);
        h.z = f2bf(v.z);
        h.w = f2bf(v.w);
        *reinterpret_cast<u16x4*>(&xb[(size_t)rb * X2ROWS * DDIM + e4 * 4]) = h;
    }
    __syncthreads();
    if (tid < X2ROWS) {
        const float* r = lds[tid];
        float halves[2];
#pragma unroll
        for (int h = 0; h < 2; ++h) {
            const float* b = r + h * 128;
            float L[16];
#pragma unroll
            for (int p = 0; p < 16; ++p) {
                float t0 = __fmul_rn(b[p], b[p]);
                float t1 = __fmul_rn(b[16 + p], b[16 + p]);
                float t2 = __fmul_rn(b[32 + p], b[32 + p]);
                float t3 = __fmul_rn(b[48 + p], b[48 + p]);
                float t4 = __fmul_rn(b[64 + p], b[64 + p]);
                float t5 = __fmul_rn(b[80 + p], b[80 + p]);
                float t6 = __fmul_rn(b[96 + p], b[96 + p]);
                float t7 = __fmul_rn(b[112 + p], b[112 + p]);
                L[p] = __fadd_rn(
                    __fadd_rn(__fadd_rn(t0, t1), __fadd_rn(t2, t3)),
                    __fadd_rn(__fadd_rn(t4, t5), __fadd_rn(t6, t7)));
            }
            float s1[8];
#pragma unroll
            for (int p = 0; p < 8; ++p) s1[p] = __fadd_rn(L[p], L[p + 8]);
            float s2[4];
#pragma unroll
            for (int p = 0; p < 4; ++p) s2[p] = __fadd_rn(s1[p], s1[p + 4]);
            float s30 = __fadd_rn(s2[0], s2[2]);
            float s31 = __fadd_rn(s2[1], s2[3]);
            halves[h] = __fadd_rn(s30, s31);
        }
        x2[(size_t)rb * X2ROWS + tid] = __fadd_rn(halves[0], halves[1]);
    }
}

// ---- e2[k]: sequential axis-0 sum (bit-exact, R6); zeroes work counters ----
__global__ __launch_bounds__(256) void vq_e2(const float* __restrict__ e,
                                             float* __restrict__ e2,
                                             int* __restrict__ counters) {
    if (blockIdx.x == 0 && threadIdx.x < 2) counters[threadIdx.x] = 0;
    int k = blockIdx.x * 256 + threadIdx.x;
    float v0 = e[k];
    float s = __fmul_rn(v0, v0);
    for (int d = 1; d < DDIM; ++d) {
        float v = e[d * KCODES + k];
        s = __fadd_rn(s, __fmul_rn(v, v));
    }
    e2[k] = s;
}

// ---- transpose E -> ET f32 + ETb bf16 --------------------------------------
__global__ __launch_bounds__(256) void vq_transpose(
    const float* __restrict__ e, float* __restrict__ et,
    unsigned short* __restrict__ etb) {
    __shared__ float tile[32][33];
    int bk = blockIdx.x;
    int bd = blockIdx.y;
    int tx = threadIdx.x & 31;
    int ty = threadIdx.x >> 5;
#pragma unroll
    for (int p = 0; p < 4; ++p)
        tile[ty + p * 8][tx] = e[(bd * 32 + ty + p * 8) * KCODES + bk * 32 + tx];
    __syncthreads();
#pragma unroll
    for (int p = 0; p < 4; ++p) {
        float v = tile[tx][ty + p * 8];
        size_t o = (size_t)(bk * 32 + ty + p * 8) * DDIM + bd * 32 + tx;
        et[o] = v;
        etb[o] = f2bf(v);
    }
}

// ---- screen: bf16 MFMA 128x128, slot-swizzled LDS, DOUBLE-BUFFERED staging -
// T3 2-phase: issue next tile's global_load_lds BEFORE computing current;
// single __syncthreads per iteration (its vmcnt(0) lands the prefetch).
__global__ __launch_bounds__(256) void vq_screen(
    const unsigned short* __restrict__ xb, const unsigned short* __restrict__ etb,
    const float* __restrict__ e2g, const float* __restrict__ x2g,
    unsigned int* __restrict__ masks, float* __restrict__ bmin) {
    __shared__ __align__(16) unsigned short Ab[2][128 * 32];
    __shared__ __align__(16) unsigned short Bb[2][128 * 32];
    __shared__ float rowmin2[2][128];
    __shared__ float e2s[128];
    __shared__ unsigned int mlds[128][4];

    const int rb = blockIdx.x;
    const int ks = blockIdx.y;
    const int row0 = rb * 128;
    const int c0 = ks * 128;
    const int tid = threadIdx.x;
    const int w = tid >> 6;
    const int lane = tid & 63;
    const int wr = w >> 1, wc = w & 1;
    const int l15 = lane & 15, l4 = lane >> 4;

    if (tid < 128) e2s[tid] = e2g[c0 + tid];
    for (int q = tid; q < 512; q += 256)
        reinterpret_cast<unsigned int*>(mlds)[q] = 0u;

    // stage one 32-d chunk into buffer `buf` (16B/lane async, swizzled source)
    auto stage = [&](int buf, int d0) {
#pragma unroll
        for (int p = 0; p < 2; ++p) {
            int idx = w * 128 + p * 64 + lane;
            int r = idx >> 2, slot = idx & 3;
            int ssl = slot ^ ((r >> 1) & 3);  // inverse slot-swizzle on source
            __builtin_amdgcn_global_load_lds(
                (glb_uint*)&xb[(size_t)(row0 + r) * DDIM + d0 + ssl * 8],
                (lds_uint*)&Ab[buf][(size_t)(w * 128 + p * 64) * 8], 16, 0, 0);
            __builtin_amdgcn_global_load_lds(
                (glb_uint*)&etb[(size_t)(c0 + r) * DDIM + d0 + ssl * 8],
                (lds_uint*)&Bb[buf][(size_t)(w * 128 + p * 64) * 8], 16, 0, 0);
        }
    };

    f32x4 acc[4][4];
#pragma unroll
    for (int i = 0; i < 4; ++i)
#pragma unroll
        for (int j = 0; j < 4; ++j) acc[i][j] = (f32x4)(0.f);

    stage(0, 0);
    __syncthreads();  // vmcnt(0): tile 0 resident; e2s/mlds visible
#pragma unroll
    for (int it = 0; it < 8; ++it) {
        const int cur = it & 1;
        if (it < 7) stage(cur ^ 1, (it + 1) * 32);  // prefetch next tile
        bf16x8 bfr[4];
#pragma unroll
        for (int j = 0; j < 4; ++j) {
            int brow = wc * 64 + j * 16 + l15;
            bfr[j] = *reinterpret_cast<const bf16x8*>(
                &Bb[cur][brow * 32 + (l4 ^ ((brow >> 1) & 3)) * 8]);
        }
#pragma unroll
        for (int i = 0; i < 4; ++i) {
            int arow = wr * 64 + i * 16 + l15;
            bf16x8 af = *reinterpret_cast<const bf16x8*>(
                &Ab[cur][arow * 32 + (l4 ^ ((arow >> 1) & 3)) * 8]);
#pragma unroll
            for (int j = 0; j < 4; ++j)
                acc[i][j] = __builtin_amdgcn_mfma_f32_16x16x32_bf16(
                    af, bfr[j], acc[i][j], 0, 0, 0);
        }
        __syncthreads();  // lands prefetch; guards buf reuse next iteration
    }

    // screen-dist = e2[k] - 2*sim. C-layout: col=lane&15, row=(lane>>4)*4+reg.
    float rm[4][4];
#pragma unroll
    for (int i = 0; i < 4; ++i)
#pragma unroll
        for (int reg = 0; reg < 4; ++reg) {
            float m = INFINITY;
#pragma unroll
            for (int j = 0; j < 4; ++j) {
                float d = e2s[wc * 64 + j * 16 + l15] - 2.f * acc[i][j][reg];
                m = fminf(m, d);
            }
            rm[i][reg] = m;
        }
#pragma unroll
    for (int m = 1; m < 16; m <<= 1)
#pragma unroll
        for (int i = 0; i < 4; ++i)
#pragma unroll
            for (int reg = 0; reg < 4; ++reg)
                rm[i][reg] = fminf(rm[i][reg], __shfl_xor(rm[i][reg], m));
    if (l15 == 0) {
#pragma unroll
        for (int i = 0; i < 4; ++i)
#pragma unroll
            for (int reg = 0; reg < 4; ++reg)
                rowmin2[wc][wr * 64 + i * 16 + l4 * 4 + reg] = rm[i][reg];
    }
    __syncthreads();

    if (tid < 128)
        bmin[(size_t)(row0 + tid) * 8 + ks] =
            fminf(rowmin2[0][tid], rowmin2[1][tid]);

#pragma unroll
    for (int i = 0; i < 4; ++i)
#pragma unroll
        for (int reg = 0; reg < 4; ++reg) {
            int rl = wr * 64 + i * 16 + l4 * 4 + reg;
            float thr = fminf(rowmin2[0][rl], rowmin2[1][rl]) +
                        screen_margin(x2g[row0 + rl]);
#pragma unroll
            for (int j = 0; j < 4; ++j) {
                int cl = wc * 64 + j * 16 + l15;
                float d = e2s[cl] - 2.f * acc[i][j][reg];
                if (d <= thr)
                    atomicOr(&mlds[rl][cl >> 5], 1u << (cl & 31));
            }
        }
    __syncthreads();
    for (int q = tid; q < 512; q += 256) {
        int r = q >> 2, wq = q & 3;
        masks[(size_t)(row0 + r) * 32 + ks * 4 + wq] = mlds[r][wq];
    }
}

// ---- pick: resolve 1-cand rows; compact 2-4-cand rows into qlist; rest flist
// qlist record: bits[0:15]=row, [16:18]=cnt, [24+10i : 24+10i+9]=k_i (asc).
__global__ __launch_bounds__(256) void vq_pick(
    const unsigned int* __restrict__ masks, const float* __restrict__ bmin,
    const float* __restrict__ x2g, int* __restrict__ idx,
    int* __restrict__ counters, unsigned long long* __restrict__ qlist,
    int* __restrict__ flist) {
    int row = blockIdx.x * 256 + threadIdx.x;  // 128 blocks
    float bm[8];
    float gmin = INFINITY;
#pragma unroll
    for (int s = 0; s < 8; ++s) {
        bm[s] = bmin[(size_t)row * 8 + s];
        gmin = fminf(gmin, bm[s]);
    }
    const float thr = gmin + screen_margin(x2g[row]);
    unsigned long long rec = 0ull;
    int cnt = 0;
#pragma unroll
    for (int q = 0; q < 8; ++q) {  // ascending q => ascending k
        if (bm[q] <= thr) {
            uint4 v = *reinterpret_cast<const uint4*>(
                &masks[(size_t)row * 32 + q * 4]);
            unsigned int wds[4] = {v.x, v.y, v.z, v.w};
#pragma unroll
            for (int ww = 0; ww < 4; ++ww) {
                unsigned int b = wds[ww];
                while (b) {
                    int t = __ffs(b) - 1;
                    if (cnt < 4)
                        rec |= (unsigned long long)(q * 128 + ww * 32 + t)
                               << (24 + 10 * cnt);
                    ++cnt;
                    b &= b - 1;
                }
            }
        }
    }
    if (cnt == 1) {
        // k*'s bit provably survives; a sole survivor must be k*
        idx[row] = (int)((rec >> 24) & (KCODES - 1));
    } else if (cnt <= 4) {
        rec |= (unsigned long long)row | ((unsigned long long)cnt << 16);
        int pos = atomicAdd(&counters[0], 1);
        qlist[pos] = rec;  // order nondeterministic; output per-row => det.
    } else {
        int pos = atomicAdd(&counters[1], 1);
        flist[pos] = row;
    }
}

// ---- rescan_quick: dense — one THREAD per candidate dot (np-exact) ---------
constexpr int QUICK_BLOCKS = 512;
__global__ __launch_bounds__(256) void vq_rescan_quick(
    const float* __restrict__ x, const float* __restrict__ et,
    const float* __restrict__ x2g, const float* __restrict__ e2g,
    const int* __restrict__ counters,
    const unsigned long long* __restrict__ qlist, int* __restrict__ idx) {
    const int nslots = counters[0] * 4;
    for (int item = blockIdx.x * 256 + threadIdx.x; item < nslots;
         item += QUICK_BLOCKS * 256) {
        const unsigned long long rec = qlist[item >> 2];
        const int row = (int)(rec & 0xFFFFull);
        const int cnt = (int)((rec >> 16) & 7ull);
        const int slot = item & 3;
        float best = INFINITY;
        int bk = 0x7fffffff;
        if (slot < cnt) {
            int k = (int)((rec >> (24 + 10 * slot)) & (KCODES - 1));
            const float4* xr =
                reinterpret_cast<const float4*>(&x[(size_t)row * DDIM]);
            const float4* er =
                reinterpret_cast<const float4*>(&et[(size_t)k * DDIM]);
            float s = 0.f;
#pragma unroll 4
            for (int g = 0; g < 64; ++g) {  // in-order d chain (np-exact)
                float4 xv = xr[g];
                float4 ev = er[g];
                s = fmaf(xv.x, ev.x, s);
                s = fmaf(xv.y, ev.y, s);
                s = fmaf(xv.z, ev.z, s);
                s = fmaf(xv.w, ev.w, s);
            }
            float u = __fadd_rn(x2g[row], e2g[k]);
            best = __fsub_rn(u, __fmul_rn(2.0f, s));
            bk = k;
        }
        // first-min reduce within the aligned 4-lane group (asc k, low-k ties)
#pragma unroll
        for (int m = 1; m < 4; m <<= 1) {
            float od = __shfl_xor(best, m);
            int oi = __shfl_xor(bk, m);
            if (od < best || (od == best && oi < bk)) {
                best = od;
                bk = oi;
            }
        }
        if (slot == 0) idx[row] = bk & (KCODES - 1);
    }
}

// ---- rescan_full: rare rows (>4 candidates); 1 wave/item, grid-stride ------
constexpr int FULL_BLOCKS = 2048;
__global__ __launch_bounds__(64) void vq_rescan_full(
    const float* __restrict__ x, const float* __restrict__ et,
    const float* __restrict__ x2g, const float* __restrict__ e2g,
    const unsigned int* __restrict__ masks, const float* __restrict__ bmin,
    const int* __restrict__ counters, const int* __restrict__ flist,
    int* __restrict__ idx) {
    __shared__ float xrow[256];
    __shared__ int cand[64];
    const int lane = threadIdx.x;
    const int n = counters[1];

    for (int item = blockIdx.x; item < n; item += FULL_BLOCKS) {
        const int row = flist[item];
        const float x2r = x2g[row];
        *reinterpret_cast<float4*>(&xrow[lane * 4]) =
            *reinterpret_cast<const float4*>(&x[(size_t)row * DDIM + lane * 4]);

        float bm = (lane < 8) ? bmin[(size_t)row * 8 + lane] : INFINITY;
        float g = bm;
#pragma unroll
        for (int m = 1; m < 8; m <<= 1) g = fminf(g, __shfl_xor(g, m));
        const float gmin = __shfl(g, 0);
        const float margin = screen_margin(x2r);
        float bmq = __shfl(bm, lane >> 2);  // all lanes execute (R11 rule)

        unsigned int wmask = 0u;
        if (lane < 32 && bmq <= gmin + margin)
            wmask = masks[(size_t)row * 32 + lane];
        int mycnt = __popc(wmask);
        int pre = mycnt;
#pragma unroll
        for (int off = 1; off < 32; off <<= 1) {
            int t = __shfl_up(pre, off);
            if (lane >= off) pre += t;
        }
        const int total = __shfl(pre, 31);
        if (lane < 32) {
            int off = pre - mycnt;  // exclusive prefix (ascending k)
            unsigned int b = wmask;
            while (b) {
                int t = __ffs(b) - 1;
                if (off < 64) cand[off] = lane * 32 + t;
                ++off;
                b &= b - 1;
            }
        }
        __builtin_amdgcn_wave_barrier();

        float best = INFINITY;
        int bk = 0x7fffffff;
        if (total <= 64) {
            if (lane < total) {
                int k = cand[lane];
                const float4* er =
                    reinterpret_cast<const float4*>(&et[(size_t)k * DDIM]);
                const float4* xr4 = reinterpret_cast<const float4*>(xrow);
                float s = 0.f;
#pragma unroll 4
                for (int g2 = 0; g2 < 64; ++g2) {
                    float4 ev = er[g2];
                    float4 xv = xr4[g2];
                    s = fmaf(xv.x, ev.x, s);
                    s = fmaf(xv.y, ev.y, s);
                    s = fmaf(xv.z, ev.z, s);
                    s = fmaf(xv.w, ev.w, s);
                }
                float u = __fadd_rn(x2r, e2g[k]);
                best = __fsub_rn(u, __fmul_rn(2.0f, s));
                bk = k;
            }
        } else {
            // cold path (margin overflow — never expected): full 1024 rescan
#pragma unroll 1
            for (int c = 0; c < 16; ++c) {
                int k = lane + c * 64;
                const float4* er =
                    reinterpret_cast<const float4*>(&et[(size_t)k * DDIM]);
                const float4* xr4 = reinterpret_cast<const float4*>(xrow);
                float s = 0.f;
#pragma unroll 4
                for (int g2 = 0; g2 < 64; ++g2) {
                    float4 ev = er[g2];
                    float4 xv = xr4[g2];
                    s = fmaf(xv.x, ev.x, s);
                    s = fmaf(xv.y, ev.y, s);
                    s = fmaf(xv.z, ev.z, s);
                    s = fmaf(xv.w, ev.w, s);
                }
                float u = __fadd_rn(x2r, e2g[k]);
                float dct = __fsub_rn(u, __fmul_rn(2.0f, s));
                if (dct < best || (dct == best && k < bk)) {
                    best = dct;
                    bk = k;
                }
            }
        }
#pragma unroll
        for (int m = 1; m < 64; m <<= 1) {
            float od = __shfl_xor(best, m);
            int oi = __shfl_xor(bk, m);
            if (od < best || (od == best && oi < bk)) {
                best = od;
                bk = oi;
            }
        }
        if (lane == 0) idx[row] = bk & (KCODES - 1);
        __builtin_amdgcn_wave_barrier();  // LDS reuse across iterations
    }
}

// ---- output: gather + fp32 STE out + loss partial (verified) ---------------
__global__ __launch_bounds__(256) void vq_output(
    const float* __restrict__ x, const float* __restrict__ et,
    const int* __restrict__ idx, float* __restrict__ out,
    float* __restrict__ blockloss) {
    __shared__ int skb[64];
    __shared__ float red[256];
    const int rb = blockIdx.x;
    const int tid = threadIdx.x;
    if (tid < 64) skb[tid] = idx[rb * 64 + tid];
    __syncthreads();
    float lsum = 0.f;
    for (int r = 0; r < 64; ++r) {
        int row = rb * 64 + r;
        int k = skb[r];
        float xv = x[(size_t)row * DDIM + tid];
        float qv = et[(size_t)k * DDIM + tid];
        float diff = __fsub_rn(qv, xv);
        float qst = __fadd_rn(xv, diff);
        out[(size_t)row * DDIM + tid] = qst;
        lsum = fmaf(diff, diff, lsum);
    }
    red[tid] = lsum;
    __syncthreads();
    for (int s = 128; s > 0; s >>= 1) {
        if (tid < s) red[tid] += red[tid + s];
        __syncthreads();
    }
    if (tid == 0) blockloss[rb] = red[0];
}

// ---- deterministic loss reduce (verified) ----------------------------------
__global__ __launch_bounds__(512) void vq_loss_reduce(
    const float* __restrict__ blockloss, float* __restrict__ out_loss) {
    __shared__ float red[512];
    int tid = threadIdx.x;
    red[tid] = blockloss[tid];
    __syncthreads();
    for (int s = 256; s > 0; s >>= 1) {
        if (tid < s) red[tid] += red[tid + s];
        __syncthreads();
    }
    if (tid == 0) {
        float m = __fmul_rn(red[0], 1.0f / (float)((size_t)NROWS * DDIM));
        out_loss[0] = __fadd_rn(__fmul_rn(0.25f, m), m);
    }
}

extern "C" void kernel_launch(void* const* d_in, const int* in_sizes, int n_in,
                              void* d_out, int out_size, void* d_ws,
                              size_t ws_size, hipStream_t stream) {
    const float* x = (const float*)d_in[0];  // [32768, 256] fp32
    const float* e = (const float*)d_in[1];  // [256, 1024]  fp32
    float* out = (float*)d_out;              // 8388608 qst + 1 loss, fp32

    float* ws = (float*)d_ws;
    float* x2 = ws;                                    // 32768
    float* e2 = x2 + NROWS;                            // 1024
    float* et = e2 + KCODES;                           // 262144
    unsigned short* etb = (unsigned short*)(et + (size_t)KCODES * DDIM);
    unsigned short* xb = etb + (size_t)KCODES * DDIM;  // 8388608 u16
    unsigned int* masks = (unsigned int*)(xb + (size_t)NROWS * DDIM);
    float* bmin = (float*)(masks + (size_t)NROWS * 32);  // 32768*8
    int* idx = (int*)(bmin + (size_t)NROWS * 8);       // 32768
    int* counters = idx + NROWS;                       // 2 (+pad to 16B)
    unsigned long long* qlist =
        (unsigned long long*)(counters + 4);           // 32768 u64
    int* flist = (int*)(qlist + NROWS);                // 32768
    float* blockloss = (float*)(flist + NROWS);        // 512

    vq_x2xb<<<NROWS / X2ROWS, 256, 0, stream>>>(x, x2, xb);
    vq_e2<<<KCODES / 256, 256, 0, stream>>>(e, e2, counters);
    vq_transpose<<<dim3(32, 8), 256, 0, stream>>>(e, et, etb);
    vq_screen<<<dim3(NROWS / 128, KCODES / 128), 256, 0, stream>>>(
        xb, etb, e2, x2, masks, bmin);
    vq_pick<<<NROWS / 256, 256, 0, stream>>>(masks, bmin, x2, idx, counters,
                                             qlist, flist);
    vq_rescan_quick<<<QUICK_BLOCKS, 256, 0, stream>>>(x, et, x2, e2, counters,
                                                      qlist, idx);
    vq_rescan_full<<<FULL_BLOCKS, 64, 0, stream>>>(x, et, x2, e2, masks, bmin,
                                                   counters, flist, idx);
    vq_output<<<NROWS / 64, 256, 0, stream>>>(x, et, idx, out, blockloss);
    vq_loss_reduce<<<1, 512, 0, stream>>>(blockloss, out + (size_t)NROWS * DDIM);
}

// Round 23
// 121.042 us; speedup vs baseline: 1.1550x; 1.1550x over previous
//
#include <hip/hip_runtime.h>
#include <math.h>

#define NROWS 32768
#define DDIM 256
#define KCODES 1024

typedef __attribute__((ext_vector_type(8))) short bf16x8;
typedef __attribute__((ext_vector_type(4))) float f32x4;
typedef __attribute__((ext_vector_type(4))) unsigned short u16x4;
typedef __attribute__((address_space(3))) unsigned int lds_uint;
typedef const __attribute__((address_space(1))) unsigned int glb_uint;

__device__ __forceinline__ unsigned short f2bf(float f) {
    unsigned int u;
    __builtin_memcpy(&u, &f, 4);
    u += 0x7fffu + ((u >> 16) & 1u);
    return (unsigned short)(u >> 16);
}

// Rigorous k*-survival margin (R17 derivation): >= 2*E + 2*dnp,
// E = 2*(2^-7*1.004 + 255*2^-24)*||x||*||e||max, ||e||max<=0.463,
// dnp <= 2.3e-4  =>  0.0146*sqrt(x2) + 4.6e-4. Field-tested R13-R22.
__device__ __forceinline__ float screen_margin(float x2v) {
    return 0.0147f * sqrtf(x2v) + 5e-4f;
}

// ---- fused: x2 (numpy AVX512 pairwise tree, bit-exact R6) + xb bf16 cast;
//      blocks >= 1024 run the e2 body (sequential axis-0 sum, bit-exact R6)
constexpr int X2ROWS = 32;
__global__ __launch_bounds__(256) void vq_x2xb_e2(
    const float* __restrict__ x, float* __restrict__ x2,
    unsigned short* __restrict__ xb, const float* __restrict__ e,
    float* __restrict__ e2, int* __restrict__ counters) {
    const int tid = threadIdx.x;
    if (blockIdx.x >= NROWS / X2ROWS) {
        // ---- e2 body (4 blocks) ----
        int eb = blockIdx.x - NROWS / X2ROWS;
        if (eb == 0 && tid < 2) counters[tid] = 0;
        int k = eb * 256 + tid;
        float v0 = e[k];
        float s = __fmul_rn(v0, v0);
        for (int d = 1; d < DDIM; ++d) {
            float v = e[d * KCODES + k];
            s = __fadd_rn(s, __fmul_rn(v, v));
        }
        e2[k] = s;
        return;
    }
    // ---- x2 + xb body (1024 blocks) ----
    __shared__ float lds[X2ROWS][257];
    const int rb = blockIdx.x;
    const float4* src =
        reinterpret_cast<const float4*>(x + (size_t)rb * X2ROWS * DDIM);
#pragma unroll
    for (int i = 0; i < 8; ++i) {
        int e4 = tid + i * 256;
        int row = e4 >> 6;
        int col = e4 & 63;
        float4 v = src[e4];
        lds[row][col * 4 + 0] = v.x;
        lds[row][col * 4 + 1] = v.y;
        lds[row][col * 4 + 2] = v.z;
        lds[row][col * 4 + 3] = v.w;
        u16x4 h;
        h.x = f2bf(v.x);
        h.y = f2bf(v.y);
        h.z = f2bf(v.z);
        h.w = f2bf(v.w);
        *reinterpret_cast<u16x4*>(&xb[(size_t)rb * X2ROWS * DDIM + e4 * 4]) = h;
    }
    __syncthreads();
    if (tid < X2ROWS) {
        const float* r = lds[tid];
        float halves[2];
#pragma unroll
        for (int h = 0; h < 2; ++h) {
            const float* b = r + h * 128;
            float L[16];
#pragma unroll
            for (int p = 0; p < 16; ++p) {
                float t0 = __fmul_rn(b[p], b[p]);
                float t1 = __fmul_rn(b[16 + p], b[16 + p]);
                float t2 = __fmul_rn(b[32 + p], b[32 + p]);
                float t3 = __fmul_rn(b[48 + p], b[48 + p]);
                float t4 = __fmul_rn(b[64 + p], b[64 + p]);
                float t5 = __fmul_rn(b[80 + p], b[80 + p]);
                float t6 = __fmul_rn(b[96 + p], b[96 + p]);
                float t7 = __fmul_rn(b[112 + p], b[112 + p]);
                L[p] = __fadd_rn(
                    __fadd_rn(__fadd_rn(t0, t1), __fadd_rn(t2, t3)),
                    __fadd_rn(__fadd_rn(t4, t5), __fadd_rn(t6, t7)));
            }
            float s1[8];
#pragma unroll
            for (int p = 0; p < 8; ++p) s1[p] = __fadd_rn(L[p], L[p + 8]);
            float s2[4];
#pragma unroll
            for (int p = 0; p < 4; ++p) s2[p] = __fadd_rn(s1[p], s1[p + 4]);
            float s30 = __fadd_rn(s2[0], s2[2]);
            float s31 = __fadd_rn(s2[1], s2[3]);
            halves[h] = __fadd_rn(s30, s31);
        }
        x2[(size_t)rb * X2ROWS + tid] = __fadd_rn(halves[0], halves[1]);
    }
}

// ---- transpose E -> ET f32 + ETb bf16 --------------------------------------
__global__ __launch_bounds__(256) void vq_transpose(
    const float* __restrict__ e, float* __restrict__ et,
    unsigned short* __restrict__ etb) {
    __shared__ float tile[32][33];
    int bk = blockIdx.x;
    int bd = blockIdx.y;
    int tx = threadIdx.x & 31;
    int ty = threadIdx.x >> 5;
#pragma unroll
    for (int p = 0; p < 4; ++p)
        tile[ty + p * 8][tx] = e[(bd * 32 + ty + p * 8) * KCODES + bk * 32 + tx];
    __syncthreads();
#pragma unroll
    for (int p = 0; p < 4; ++p) {
        float v = tile[tx][ty + p * 8];
        size_t o = (size_t)(bk * 32 + ty + p * 8) * DDIM + bd * 32 + tx;
        et[o] = v;
        etb[o] = f2bf(v);
    }
}

// ---- screen: bf16 MFMA 128x128 + gll staging with SLOT-SWIZZLED LDS --------
// (R21-proven: 43.5 us, 45K conflicts, bit-identical masks)
__global__ __launch_bounds__(256) void vq_screen(
    const unsigned short* __restrict__ xb, const unsigned short* __restrict__ etb,
    const float* __restrict__ e2g, const float* __restrict__ x2g,
    unsigned int* __restrict__ masks, float* __restrict__ bmin) {
    __shared__ __align__(16) unsigned short Ab[128 * 32];
    __shared__ __align__(16) unsigned short Bb[128 * 32];
    __shared__ float rowmin2[2][128];
    __shared__ unsigned int mlds[128][4];

    const int rb = blockIdx.x;
    const int ks = blockIdx.y;
    const int row0 = rb * 128;
    const int c0 = ks * 128;
    const int tid = threadIdx.x;
    const int w = tid >> 6;
    const int lane = tid & 63;
    const int wr = w >> 1, wc = w & 1;
    const int l15 = lane & 15, l4 = lane >> 4;

    for (int q = tid; q < 512; q += 256)
        reinterpret_cast<unsigned int*>(mlds)[q] = 0u;

    f32x4 acc[4][4];
#pragma unroll
    for (int i = 0; i < 4; ++i)
#pragma unroll
        for (int j = 0; j < 4; ++j) acc[i][j] = (f32x4)(0.f);

    for (int d0 = 0; d0 < DDIM; d0 += 32) {
#pragma unroll
        for (int p = 0; p < 2; ++p) {
            int idx = w * 128 + p * 64 + lane;
            int r = idx >> 2, slot = idx & 3;
            int ssl = slot ^ ((r >> 1) & 3);  // inverse slot-swizzle on source
            const unsigned short* ga =
                &xb[(size_t)(row0 + r) * DDIM + d0 + ssl * 8];
            __builtin_amdgcn_global_load_lds(
                (glb_uint*)ga, (lds_uint*)&Ab[(size_t)(w * 128 + p * 64) * 8],
                16, 0, 0);
            const unsigned short* gb =
                &etb[(size_t)(c0 + r) * DDIM + d0 + ssl * 8];
            __builtin_amdgcn_global_load_lds(
                (glb_uint*)gb, (lds_uint*)&Bb[(size_t)(w * 128 + p * 64) * 8],
                16, 0, 0);
        }
        __syncthreads();
        bf16x8 bfr[4];
#pragma unroll
        for (int j = 0; j < 4; ++j) {
            int brow = wc * 64 + j * 16 + l15;
            bfr[j] = *reinterpret_cast<const bf16x8*>(
                &Bb[brow * 32 + (l4 ^ ((brow >> 1) & 3)) * 8]);
        }
#pragma unroll
        for (int i = 0; i < 4; ++i) {
            int arow = wr * 64 + i * 16 + l15;
            bf16x8 af = *reinterpret_cast<const bf16x8*>(
                &Ab[arow * 32 + (l4 ^ ((arow >> 1) & 3)) * 8]);
#pragma unroll
            for (int j = 0; j < 4; ++j)
                acc[i][j] = __builtin_amdgcn_mfma_f32_16x16x32_bf16(
                    af, bfr[j], acc[i][j], 0, 0, 0);
        }
        __syncthreads();
    }

    // screen-dist = e2[k] - 2*sim. C-layout: col=lane&15, row=(lane>>4)*4+reg.
    float rm[4][4];
#pragma unroll
    for (int i = 0; i < 4; ++i)
#pragma unroll
        for (int reg = 0; reg < 4; ++reg) {
            float m = INFINITY;
#pragma unroll
            for (int j = 0; j < 4; ++j) {
                float d = e2g[c0 + wc * 64 + j * 16 + l15] -
                          2.f * acc[i][j][reg];
                m = fminf(m, d);
            }
            rm[i][reg] = m;
        }
#pragma unroll
    for (int m = 1; m < 16; m <<= 1)
#pragma unroll
        for (int i = 0; i < 4; ++i)
#pragma unroll
            for (int reg = 0; reg < 4; ++reg)
                rm[i][reg] = fminf(rm[i][reg], __shfl_xor(rm[i][reg], m));
    if (l15 == 0) {
#pragma unroll
        for (int i = 0; i < 4; ++i)
#pragma unroll
            for (int reg = 0; reg < 4; ++reg)
                rowmin2[wc][wr * 64 + i * 16 + l4 * 4 + reg] = rm[i][reg];
    }
    __syncthreads();

    if (tid < 128)
        bmin[(size_t)(row0 + tid) * 8 + ks] =
            fminf(rowmin2[0][tid], rowmin2[1][tid]);

#pragma unroll
    for (int i = 0; i < 4; ++i)
#pragma unroll
        for (int reg = 0; reg < 4; ++reg) {
            int rl = wr * 64 + i * 16 + l4 * 4 + reg;
            float thr = fminf(rowmin2[0][rl], rowmin2[1][rl]) +
                        screen_margin(x2g[row0 + rl]);
#pragma unroll
            for (int j = 0; j < 4; ++j) {
                int cl = wc * 64 + j * 16 + l15;
                float d = e2g[c0 + cl] - 2.f * acc[i][j][reg];
                if (d <= thr)
                    atomicOr(&mlds[rl][cl >> 5], 1u << (cl & 31));
            }
        }
    __syncthreads();
    for (int q = tid; q < 512; q += 256) {
        int r = q >> 2, wq = q & 3;
        masks[(size_t)(row0 + r) * 32 + ks * 4 + wq] = mlds[r][wq];
    }
}

// ---- pick: resolve 1-cand rows; compact 2-4-cand rows into qlist; rest flist
// qlist record: bits[0:15]=row, [16:18]=cnt, [24+10i : 24+10i+9]=k_i (asc).
__global__ __launch_bounds__(256) void vq_pick(
    const unsigned int* __restrict__ masks, const float* __restrict__ bmin,
    const float* __restrict__ x2g, int* __restrict__ idx,
    int* __restrict__ counters, unsigned long long* __restrict__ qlist,
    int* __restrict__ flist) {
    int row = blockIdx.x * 256 + threadIdx.x;  // 128 blocks
    float bm[8];
    float gmin = INFINITY;
#pragma unroll
    for (int s = 0; s < 8; ++s) {
        bm[s] = bmin[(size_t)row * 8 + s];
        gmin = fminf(gmin, bm[s]);
    }
    const float thr = gmin + screen_margin(x2g[row]);
    unsigned long long rec = 0ull;
    int cnt = 0;
#pragma unroll
    for (int q = 0; q < 8; ++q) {  // ascending q => ascending k
        if (bm[q] <= thr) {
            uint4 v = *reinterpret_cast<const uint4*>(
                &masks[(size_t)row * 32 + q * 4]);
            unsigned int wds[4] = {v.x, v.y, v.z, v.w};
#pragma unroll
            for (int ww = 0; ww < 4; ++ww) {
                unsigned int b = wds[ww];
                while (b) {
                    int t = __ffs(b) - 1;
                    if (cnt < 4)
                        rec |= (unsigned long long)(q * 128 + ww * 32 + t)
                               << (24 + 10 * cnt);
                    ++cnt;
                    b &= b - 1;
                }
            }
        }
    }
    if (cnt == 1) {
        // k*'s bit provably survives; a sole survivor must be k*
        idx[row] = (int)((rec >> 24) & (KCODES - 1));
    } else if (cnt <= 4) {
        rec |= (unsigned long long)row | ((unsigned long long)cnt << 16);
        int pos = atomicAdd(&counters[0], 1);
        qlist[pos] = rec;  // order nondeterministic; output per-row => det.
    } else {
        int pos = atomicAdd(&counters[1], 1);
        flist[pos] = row;
    }
}

// ---- rescan (merged): blocks <512 = quick (thread/dot); rest = full --------
constexpr int QUICK_BLOCKS = 512;
constexpr int FULL_BLOCKS = 2048;
__global__ __launch_bounds__(256) void vq_rescan(
    const float* __restrict__ x, const float* __restrict__ et,
    const float* __restrict__ x2g, const float* __restrict__ e2g,
    const unsigned int* __restrict__ masks, const float* __restrict__ bmin,
    const int* __restrict__ counters, const unsigned long long* __restrict__ qlist,
    const int* __restrict__ flist, int* __restrict__ idx) {
    __shared__ float xrow[256];
    __shared__ int cand[64];

    if (blockIdx.x < QUICK_BLOCKS) {
        // ---- quick body: one thread per candidate dot (np-exact) ----
        const int nslots = counters[0] * 4;
        for (int item = blockIdx.x * 256 + threadIdx.x; item < nslots;
             item += QUICK_BLOCKS * 256) {
            const unsigned long long rec = qlist[item >> 2];
            const int row = (int)(rec & 0xFFFFull);
            const int cnt = (int)((rec >> 16) & 7ull);
            const int slot = item & 3;
            float best = INFINITY;
            int bk = 0x7fffffff;
            if (slot < cnt) {
                int k = (int)((rec >> (24 + 10 * slot)) & (KCODES - 1));
                const float4* xr =
                    reinterpret_cast<const float4*>(&x[(size_t)row * DDIM]);
                const float4* er =
                    reinterpret_cast<const float4*>(&et[(size_t)k * DDIM]);
                float s = 0.f;
#pragma unroll 4
                for (int g = 0; g < 64; ++g) {  // in-order d chain (np-exact)
                    float4 xv = xr[g];
                    float4 ev = er[g];
                    s = fmaf(xv.x, ev.x, s);
                    s = fmaf(xv.y, ev.y, s);
                    s = fmaf(xv.z, ev.z, s);
                    s = fmaf(xv.w, ev.w, s);
                }
                float u = __fadd_rn(x2g[row], e2g[k]);
                best = __fsub_rn(u, __fmul_rn(2.0f, s));
                bk = k;
            }
            // first-min reduce within aligned 4-lane group (asc k, low-k ties)
#pragma unroll
            for (int m = 1; m < 4; m <<= 1) {
                float od = __shfl_xor(best, m);
                int oi = __shfl_xor(bk, m);
                if (od < best || (od == best && oi < bk)) {
                    best = od;
                    bk = oi;
                }
            }
            if (slot == 0) idx[row] = bk & (KCODES - 1);
        }
        return;
    }

    // ---- full body: rare rows (>4 cands); wave 0 only, no block barriers ---
    if (threadIdx.x >= 64) return;
    const int lane = threadIdx.x;
    const int n = counters[1];
    for (int item = (int)blockIdx.x - QUICK_BLOCKS; item < n;
         item += FULL_BLOCKS) {
        const int row = flist[item];
        const float x2r = x2g[row];
        *reinterpret_cast<float4*>(&xrow[lane * 4]) =
            *reinterpret_cast<const float4*>(&x[(size_t)row * DDIM + lane * 4]);

        float bm = (lane < 8) ? bmin[(size_t)row * 8 + lane] : INFINITY;
        float g = bm;
#pragma unroll
        for (int m = 1; m < 8; m <<= 1) g = fminf(g, __shfl_xor(g, m));
        const float gmin = __shfl(g, 0);
        const float margin = screen_margin(x2r);
        float bmq = __shfl(bm, lane >> 2);  // all lanes execute (R11 rule)

        unsigned int wmask = 0u;
        if (lane < 32 && bmq <= gmin + margin)
            wmask = masks[(size_t)row * 32 + lane];
        int mycnt = __popc(wmask);
        int pre = mycnt;
#pragma unroll
        for (int off = 1; off < 32; off <<= 1) {
            int t = __shfl_up(pre, off);
            if (lane >= off) pre += t;
        }
        const int total = __shfl(pre, 31);
        if (lane < 32) {
            int off = pre - mycnt;  // exclusive prefix (ascending k)
            unsigned int b = wmask;
            while (b) {
                int t = __ffs(b) - 1;
                if (off < 64) cand[off] = lane * 32 + t;
                ++off;
                b &= b - 1;
            }
        }
        __builtin_amdgcn_wave_barrier();

        float best = INFINITY;
        int bk = 0x7fffffff;
        if (total <= 64) {
            if (lane < total) {
                int k = cand[lane];
                const float4* er =
                    reinterpret_cast<const float4*>(&et[(size_t)k * DDIM]);
                const float4* xr4 = reinterpret_cast<const float4*>(xrow);
                float s = 0.f;
#pragma unroll 4
                for (int g2 = 0; g2 < 64; ++g2) {
                    float4 ev = er[g2];
                    float4 xv = xr4[g2];
                    s = fmaf(xv.x, ev.x, s);
                    s = fmaf(xv.y, ev.y, s);
                    s = fmaf(xv.z, ev.z, s);
                    s = fmaf(xv.w, ev.w, s);
                }
                float u = __fadd_rn(x2r, e2g[k]);
                best = __fsub_rn(u, __fmul_rn(2.0f, s));
                bk = k;
            }
        } else {
            // cold path (margin overflow — never expected): full 1024 rescan
#pragma unroll 1
            for (int c = 0; c < 16; ++c) {
                int k = lane + c * 64;
                const float4* er =
                    reinterpret_cast<const float4*>(&et[(size_t)k * DDIM]);
                const float4* xr4 = reinterpret_cast<const float4*>(xrow);
                float s = 0.f;
#pragma unroll 4
                for (int g2 = 0; g2 < 64; ++g2) {
                    float4 ev = er[g2];
                    float4 xv = xr4[g2];
                    s = fmaf(xv.x, ev.x, s);
                    s = fmaf(xv.y, ev.y, s);
                    s = fmaf(xv.z, ev.z, s);
                    s = fmaf(xv.w, ev.w, s);
                }
                float u = __fadd_rn(x2r, e2g[k]);
                float dct = __fsub_rn(u, __fmul_rn(2.0f, s));
                if (dct < best || (dct == best && k < bk)) {
                    best = dct;
                    bk = k;
                }
            }
        }
#pragma unroll
        for (int m = 1; m < 64; m <<= 1) {
            float od = __shfl_xor(best, m);
            int oi = __shfl_xor(bk, m);
            if (od < best || (od == best && oi < bk)) {
                best = od;
                bk = oi;
            }
        }
        if (lane == 0) idx[row] = bk & (KCODES - 1);
        __builtin_amdgcn_wave_barrier();  // LDS reuse across iterations
    }
}

// ---- output: gather + fp32 STE out + loss partial (verified) ---------------
__global__ __launch_bounds__(256) void vq_output(
    const float* __restrict__ x, const float* __restrict__ et,
    const int* __restrict__ idx, float* __restrict__ out,
    float* __restrict__ blockloss) {
    __shared__ int skb[64];
    __shared__ float red[256];
    const int rb = blockIdx.x;
    const int tid = threadIdx.x;
    if (tid < 64) skb[tid] = idx[rb * 64 + tid];
    __syncthreads();
    float lsum = 0.f;
    for (int r = 0; r < 64; ++r) {
        int row = rb * 64 + r;
        int k = skb[r];
        float xv = x[(size_t)row * DDIM + tid];
        float qv = et[(size_t)k * DDIM + tid];
        float diff = __fsub_rn(qv, xv);
        float qst = __fadd_rn(xv, diff);
        out[(size_t)row * DDIM + tid] = qst;
        lsum = fmaf(diff, diff, lsum);
    }
    red[tid] = lsum;
    __syncthreads();
    for (int s = 128; s > 0; s >>= 1) {
        if (tid < s) red[tid] += red[tid + s];
        __syncthreads();
    }
    if (tid == 0) blockloss[rb] = red[0];
}

// ---- deterministic loss reduce (verified) ----------------------------------
__global__ __launch_bounds__(512) void vq_loss_reduce(
    const float* __restrict__ blockloss, float* __restrict__ out_loss) {
    __shared__ float red[512];
    int tid = threadIdx.x;
    red[tid] = blockloss[tid];
    __syncthreads();
    for (int s = 256; s > 0; s >>= 1) {
        if (tid < s) red[tid] += red[tid + s];
        __syncthreads();
    }
    if (tid == 0) {
        float m = __fmul_rn(red[0], 1.0f / (float)((size_t)NROWS * DDIM));
        out_loss[0] = __fadd_rn(__fmul_rn(0.25f, m), m);
    }
}

extern "C" void kernel_launch(void* const* d_in, const int* in_sizes, int n_in,
                              void* d_out, int out_size, void* d_ws,
                              size_t ws_size, hipStream_t stream) {
    const float* x = (const float*)d_in[0];  // [32768, 256] fp32
    const float* e = (const float*)d_in[1];  // [256, 1024]  fp32
    float* out = (float*)d_out;              // 8388608 qst + 1 loss, fp32

    float* ws = (float*)d_ws;
    float* x2 = ws;                                    // 32768
    float* e2 = x2 + NROWS;                            // 1024
    float* et = e2 + KCODES;                           // 262144
    unsigned short* etb = (unsigned short*)(et + (size_t)KCODES * DDIM);
    unsigned short* xb = etb + (size_t)KCODES * DDIM;  // 8388608 u16
    unsigned int* masks = (unsigned int*)(xb + (size_t)NROWS * DDIM);
    float* bmin = (float*)(masks + (size_t)NROWS * 32);  // 32768*8
    int* idx = (int*)(bmin + (size_t)NROWS * 8);       // 32768
    int* counters = idx + NROWS;                       // 2 (+pad to 16B)
    unsigned long long* qlist =
        (unsigned long long*)(counters + 4);           // 32768 u64
    int* flist = (int*)(qlist + NROWS);                // 32768
    float* blockloss = (float*)(flist + NROWS);        // 512

    vq_x2xb_e2<<<NROWS / X2ROWS + KCODES / 256, 256, 0, stream>>>(
        x, x2, xb, e, e2, counters);
    vq_transpose<<<dim3(32, 8), 256, 0, stream>>>(e, et, etb);
    vq_screen<<<dim3(NROWS / 128, KCODES / 128), 256, 0, stream>>>(
        xb, etb, e2, x2, masks, bmin);
    vq_pick<<<NROWS / 256, 256, 0, stream>>>(masks, bmin, x2, idx, counters,
                                             qlist, flist);
    vq_rescan<<<QUICK_BLOCKS + FULL_BLOCKS, 256, 0, stream>>>(
        x, et, x2, e2, masks, bmin, counters, qlist, flist, idx);
    vq_output<<<NROWS / 64, 256, 0, stream>>>(x, et, idx, out, blockloss);
    vq_loss_reduce<<<1, 512, 0, stream>>>(blockloss, out + (size_t)NROWS * DDIM);
}

// Round 24
// 118.493 us; speedup vs baseline: 1.1799x; 1.0215x over previous
//
#include <hip/hip_runtime.h>
#include <math.h>

#define NROWS 32768
#define DDIM 256
#define KCODES 1024

typedef __attribute__((ext_vector_type(8))) short bf16x8;
typedef __attribute__((ext_vector_type(4))) float f32x4;
typedef __attribute__((ext_vector_type(4))) unsigned short u16x4;
typedef __attribute__((address_space(3))) unsigned int lds_uint;
typedef const __attribute__((address_space(1))) unsigned int glb_uint;

__device__ __forceinline__ unsigned short f2bf(float f) {
    unsigned int u;
    __builtin_memcpy(&u, &f, 4);
    u += 0x7fffu + ((u >> 16) & 1u);
    return (unsigned short)(u >> 16);
}

// Rigorous k*-survival margin (R17 derivation): >= 2*E + 2*dnp,
// E = 2*(2^-7*1.004 + 255*2^-24)*||x||*||e||max, ||e||max<=0.463,
// dnp <= 2.3e-4  =>  0.0146*sqrt(x2) + 4.6e-4. Field-tested R13-R23.
__device__ __forceinline__ float screen_margin(float x2v) {
    return 0.0147f * sqrtf(x2v) + 5e-4f;
}

// ---- fused front kernel, three block ranges:
//  [0, 1024)      : x2 (numpy AVX512 pairwise tree, bit-exact R6) + xb cast
//  [1024, 1028)   : e2 (sequential axis-0 sum, bit-exact R6) + counter zero
//  [1028, 1284)   : transpose E -> ET f32 + ETb bf16 (exact copy)
constexpr int X2ROWS = 32;
constexpr int X2BLK = NROWS / X2ROWS;          // 1024
constexpr int E2BLK = KCODES / 256;            // 4
__global__ __launch_bounds__(256) void vq_front(
    const float* __restrict__ x, float* __restrict__ x2,
    unsigned short* __restrict__ xb, const float* __restrict__ e,
    float* __restrict__ e2, float* __restrict__ et,
    unsigned short* __restrict__ etb, int* __restrict__ counters) {
    __shared__ float shbuf[X2ROWS * 257];  // reused by x2 and transpose bodies
    const int tid = threadIdx.x;
    const int b = blockIdx.x;

    if (b >= X2BLK + E2BLK) {
        // ---- transpose body (256 blocks) ----
        int tb = b - X2BLK - E2BLK;
        int bk = tb & 31;   // k-tile
        int bd = tb >> 5;   // d-tile
        int tx = tid & 31;
        int ty = tid >> 5;
        // tile[r][c] at shbuf[r*33 + c]
#pragma unroll
        for (int p = 0; p < 4; ++p)
            shbuf[(ty + p * 8) * 33 + tx] =
                e[(bd * 32 + ty + p * 8) * KCODES + bk * 32 + tx];
        __syncthreads();
#pragma unroll
        for (int p = 0; p < 4; ++p) {
            float v = shbuf[tx * 33 + ty + p * 8];
            size_t o = (size_t)(bk * 32 + ty + p * 8) * DDIM + bd * 32 + tx;
            et[o] = v;
            etb[o] = f2bf(v);
        }
        return;
    }
    if (b >= X2BLK) {
        // ---- e2 body (4 blocks) ----
        int eb = b - X2BLK;
        if (eb == 0 && tid < 2) counters[tid] = 0;
        int k = eb * 256 + tid;
        float v0 = e[k];
        float s = __fmul_rn(v0, v0);
        for (int d = 1; d < DDIM; ++d) {
            float v = e[d * KCODES + k];
            s = __fadd_rn(s, __fmul_rn(v, v));
        }
        e2[k] = s;
        return;
    }
    // ---- x2 + xb body (1024 blocks); lds[row][col] at shbuf[row*257+col] ---
    const int rb = b;
    const float4* src =
        reinterpret_cast<const float4*>(x + (size_t)rb * X2ROWS * DDIM);
#pragma unroll
    for (int i = 0; i < 8; ++i) {
        int e4 = tid + i * 256;
        int row = e4 >> 6;
        int col = e4 & 63;
        float4 v = src[e4];
        shbuf[row * 257 + col * 4 + 0] = v.x;
        shbuf[row * 257 + col * 4 + 1] = v.y;
        shbuf[row * 257 + col * 4 + 2] = v.z;
        shbuf[row * 257 + col * 4 + 3] = v.w;
        u16x4 h;
        h.x = f2bf(v.x);
        h.y = f2bf(v.y);
        h.z = f2bf(v.z);
        h.w = f2bf(v.w);
        *reinterpret_cast<u16x4*>(&xb[(size_t)rb * X2ROWS * DDIM + e4 * 4]) = h;
    }
    __syncthreads();
    if (tid < X2ROWS) {
        const float* r = &shbuf[tid * 257];
        float halves[2];
#pragma unroll
        for (int h = 0; h < 2; ++h) {
            const float* bp = r + h * 128;
            float L[16];
#pragma unroll
            for (int p = 0; p < 16; ++p) {
                float t0 = __fmul_rn(bp[p], bp[p]);
                float t1 = __fmul_rn(bp[16 + p], bp[16 + p]);
                float t2 = __fmul_rn(bp[32 + p], bp[32 + p]);
                float t3 = __fmul_rn(bp[48 + p], bp[48 + p]);
                float t4 = __fmul_rn(bp[64 + p], bp[64 + p]);
                float t5 = __fmul_rn(bp[80 + p], bp[80 + p]);
                float t6 = __fmul_rn(bp[96 + p], bp[96 + p]);
                float t7 = __fmul_rn(bp[112 + p], bp[112 + p]);
                L[p] = __fadd_rn(
                    __fadd_rn(__fadd_rn(t0, t1), __fadd_rn(t2, t3)),
                    __fadd_rn(__fadd_rn(t4, t5), __fadd_rn(t6, t7)));
            }
            float s1[8];
#pragma unroll
            for (int p = 0; p < 8; ++p) s1[p] = __fadd_rn(L[p], L[p + 8]);
            float s2[4];
#pragma unroll
            for (int p = 0; p < 4; ++p) s2[p] = __fadd_rn(s1[p], s1[p + 4]);
            float s30 = __fadd_rn(s2[0], s2[2]);
            float s31 = __fadd_rn(s2[1], s2[3]);
            halves[h] = __fadd_rn(s30, s31);
        }
        x2[(size_t)rb * X2ROWS + tid] = __fadd_rn(halves[0], halves[1]);
    }
}

// ---- screen: bf16 MFMA 128x128 + gll staging with SLOT-SWIZZLED LDS --------
// (R21-proven: 43.5 us, 45K conflicts, bit-identical masks)
__global__ __launch_bounds__(256) void vq_screen(
    const unsigned short* __restrict__ xb, const unsigned short* __restrict__ etb,
    const float* __restrict__ e2g, const float* __restrict__ x2g,
    unsigned int* __restrict__ masks, float* __restrict__ bmin) {
    __shared__ __align__(16) unsigned short Ab[128 * 32];
    __shared__ __align__(16) unsigned short Bb[128 * 32];
    __shared__ float rowmin2[2][128];
    __shared__ unsigned int mlds[128][4];

    const int rb = blockIdx.x;
    const int ks = blockIdx.y;
    const int row0 = rb * 128;
    const int c0 = ks * 128;
    const int tid = threadIdx.x;
    const int w = tid >> 6;
    const int lane = tid & 63;
    const int wr = w >> 1, wc = w & 1;
    const int l15 = lane & 15, l4 = lane >> 4;

    for (int q = tid; q < 512; q += 256)
        reinterpret_cast<unsigned int*>(mlds)[q] = 0u;

    f32x4 acc[4][4];
#pragma unroll
    for (int i = 0; i < 4; ++i)
#pragma unroll
        for (int j = 0; j < 4; ++j) acc[i][j] = (f32x4)(0.f);

    for (int d0 = 0; d0 < DDIM; d0 += 32) {
#pragma unroll
        for (int p = 0; p < 2; ++p) {
            int idx = w * 128 + p * 64 + lane;
            int r = idx >> 2, slot = idx & 3;
            int ssl = slot ^ ((r >> 1) & 3);  // inverse slot-swizzle on source
            const unsigned short* ga =
                &xb[(size_t)(row0 + r) * DDIM + d0 + ssl * 8];
            __builtin_amdgcn_global_load_lds(
                (glb_uint*)ga, (lds_uint*)&Ab[(size_t)(w * 128 + p * 64) * 8],
                16, 0, 0);
            const unsigned short* gb =
                &etb[(size_t)(c0 + r) * DDIM + d0 + ssl * 8];
            __builtin_amdgcn_global_load_lds(
                (glb_uint*)gb, (lds_uint*)&Bb[(size_t)(w * 128 + p * 64) * 8],
                16, 0, 0);
        }
        __syncthreads();
        bf16x8 bfr[4];
#pragma unroll
        for (int j = 0; j < 4; ++j) {
            int brow = wc * 64 + j * 16 + l15;
            bfr[j] = *reinterpret_cast<const bf16x8*>(
                &Bb[brow * 32 + (l4 ^ ((brow >> 1) & 3)) * 8]);
        }
#pragma unroll
        for (int i = 0; i < 4; ++i) {
            int arow = wr * 64 + i * 16 + l15;
            bf16x8 af = *reinterpret_cast<const bf16x8*>(
                &Ab[arow * 32 + (l4 ^ ((arow >> 1) & 3)) * 8]);
#pragma unroll
            for (int j = 0; j < 4; ++j)
                acc[i][j] = __builtin_amdgcn_mfma_f32_16x16x32_bf16(
                    af, bfr[j], acc[i][j], 0, 0, 0);
        }
        __syncthreads();
    }

    // screen-dist = e2[k] - 2*sim. C-layout: col=lane&15, row=(lane>>4)*4+reg.
    float rm[4][4];
#pragma unroll
    for (int i = 0; i < 4; ++i)
#pragma unroll
        for (int reg = 0; reg < 4; ++reg) {
            float m = INFINITY;
#pragma unroll
            for (int j = 0; j < 4; ++j) {
                float d = e2g[c0 + wc * 64 + j * 16 + l15] -
                          2.f * acc[i][j][reg];
                m = fminf(m, d);
            }
            rm[i][reg] = m;
        }
#pragma unroll
    for (int m = 1; m < 16; m <<= 1)
#pragma unroll
        for (int i = 0; i < 4; ++i)
#pragma unroll
            for (int reg = 0; reg < 4; ++reg)
                rm[i][reg] = fminf(rm[i][reg], __shfl_xor(rm[i][reg], m));
    if (l15 == 0) {
#pragma unroll
        for (int i = 0; i < 4; ++i)
#pragma unroll
            for (int reg = 0; reg < 4; ++reg)
                rowmin2[wc][wr * 64 + i * 16 + l4 * 4 + reg] = rm[i][reg];
    }
    __syncthreads();

    if (tid < 128)
        bmin[(size_t)(row0 + tid) * 8 + ks] =
            fminf(rowmin2[0][tid], rowmin2[1][tid]);

#pragma unroll
    for (int i = 0; i < 4; ++i)
#pragma unroll
        for (int reg = 0; reg < 4; ++reg) {
            int rl = wr * 64 + i * 16 + l4 * 4 + reg;
            float thr = fminf(rowmin2[0][rl], rowmin2[1][rl]) +
                        screen_margin(x2g[row0 + rl]);
#pragma unroll
            for (int j = 0; j < 4; ++j) {
                int cl = wc * 64 + j * 16 + l15;
                float d = e2g[c0 + cl] - 2.f * acc[i][j][reg];
                if (d <= thr)
                    atomicOr(&mlds[rl][cl >> 5], 1u << (cl & 31));
            }
        }
    __syncthreads();
    for (int q = tid; q < 512; q += 256) {
        int r = q >> 2, wq = q & 3;
        masks[(size_t)(row0 + r) * 32 + ks * 4 + wq] = mlds[r][wq];
    }
}

// ---- pick: resolve 1-cand rows; compact 2-4-cand rows into qlist; rest flist
// qlist record: bits[0:15]=row, [16:18]=cnt, [24+10i : 24+10i+9]=k_i (asc).
__global__ __launch_bounds__(256) void vq_pick(
    const unsigned int* __restrict__ masks, const float* __restrict__ bmin,
    const float* __restrict__ x2g, int* __restrict__ idx,
    int* __restrict__ counters, unsigned long long* __restrict__ qlist,
    int* __restrict__ flist) {
    int row = blockIdx.x * 256 + threadIdx.x;  // 128 blocks
    float bm[8];
    float gmin = INFINITY;
#pragma unroll
    for (int s = 0; s < 8; ++s) {
        bm[s] = bmin[(size_t)row * 8 + s];
        gmin = fminf(gmin, bm[s]);
    }
    const float thr = gmin + screen_margin(x2g[row]);
    unsigned long long rec = 0ull;
    int cnt = 0;
#pragma unroll
    for (int q = 0; q < 8; ++q) {  // ascending q => ascending k
        if (bm[q] <= thr) {
            uint4 v = *reinterpret_cast<const uint4*>(
                &masks[(size_t)row * 32 + q * 4]);
            unsigned int wds[4] = {v.x, v.y, v.z, v.w};
#pragma unroll
            for (int ww = 0; ww < 4; ++ww) {
                unsigned int b = wds[ww];
                while (b) {
                    int t = __ffs(b) - 1;
                    if (cnt < 4)
                        rec |= (unsigned long long)(q * 128 + ww * 32 + t)
                               << (24 + 10 * cnt);
                    ++cnt;
                    b &= b - 1;
                }
            }
        }
    }
    if (cnt == 1) {
        // k*'s bit provably survives; a sole survivor must be k*
        idx[row] = (int)((rec >> 24) & (KCODES - 1));
    } else if (cnt <= 4) {
        rec |= (unsigned long long)row | ((unsigned long long)cnt << 16);
        int pos = atomicAdd(&counters[0], 1);
        qlist[pos] = rec;  // order nondeterministic; output per-row => det.
    } else {
        int pos = atomicAdd(&counters[1], 1);
        flist[pos] = row;
    }
}

// ---- rescan (merged): blocks <512 = quick (thread/dot); rest = full --------
constexpr int QUICK_BLOCKS = 512;
constexpr int FULL_BLOCKS = 2048;
__global__ __launch_bounds__(256) void vq_rescan(
    const float* __restrict__ x, const float* __restrict__ et,
    const float* __restrict__ x2g, const float* __restrict__ e2g,
    const unsigned int* __restrict__ masks, const float* __restrict__ bmin,
    const int* __restrict__ counters, const unsigned long long* __restrict__ qlist,
    const int* __restrict__ flist, int* __restrict__ idx) {
    __shared__ float xrow[256];
    __shared__ int cand[64];

    if (blockIdx.x < QUICK_BLOCKS) {
        // ---- quick body: one thread per candidate dot (np-exact) ----
        const int nslots = counters[0] * 4;
        for (int item = blockIdx.x * 256 + threadIdx.x; item < nslots;
             item += QUICK_BLOCKS * 256) {
            const unsigned long long rec = qlist[item >> 2];
            const int row = (int)(rec & 0xFFFFull);
            const int cnt = (int)((rec >> 16) & 7ull);
            const int slot = item & 3;
            float best = INFINITY;
            int bk = 0x7fffffff;
            if (slot < cnt) {
                int k = (int)((rec >> (24 + 10 * slot)) & (KCODES - 1));
                const float4* xr =
                    reinterpret_cast<const float4*>(&x[(size_t)row * DDIM]);
                const float4* er =
                    reinterpret_cast<const float4*>(&et[(size_t)k * DDIM]);
                float s = 0.f;
#pragma unroll 4
                for (int g = 0; g < 64; ++g) {  // in-order d chain (np-exact)
                    float4 xv = xr[g];
                    float4 ev = er[g];
                    s = fmaf(xv.x, ev.x, s);
                    s = fmaf(xv.y, ev.y, s);
                    s = fmaf(xv.z, ev.z, s);
                    s = fmaf(xv.w, ev.w, s);
                }
                float u = __fadd_rn(x2g[row], e2g[k]);
                best = __fsub_rn(u, __fmul_rn(2.0f, s));
                bk = k;
            }
            // first-min reduce within aligned 4-lane group (asc k, low-k ties)
#pragma unroll
            for (int m = 1; m < 4; m <<= 1) {
                float od = __shfl_xor(best, m);
                int oi = __shfl_xor(bk, m);
                if (od < best || (od == best && oi < bk)) {
                    best = od;
                    bk = oi;
                }
            }
            if (slot == 0) idx[row] = bk & (KCODES - 1);
        }
        return;
    }

    // ---- full body: rare rows (>4 cands); wave 0 only, no block barriers ---
    if (threadIdx.x >= 64) return;
    const int lane = threadIdx.x;
    const int n = counters[1];
    for (int item = (int)blockIdx.x - QUICK_BLOCKS; item < n;
         item += FULL_BLOCKS) {
        const int row = flist[item];
        const float x2r = x2g[row];
        *reinterpret_cast<float4*>(&xrow[lane * 4]) =
            *reinterpret_cast<const float4*>(&x[(size_t)row * DDIM + lane * 4]);

        float bm = (lane < 8) ? bmin[(size_t)row * 8 + lane] : INFINITY;
        float g = bm;
#pragma unroll
        for (int m = 1; m < 8; m <<= 1) g = fminf(g, __shfl_xor(g, m));
        const float gmin = __shfl(g, 0);
        const float margin = screen_margin(x2r);
        float bmq = __shfl(bm, lane >> 2);  // all lanes execute (R11 rule)

        unsigned int wmask = 0u;
        if (lane < 32 && bmq <= gmin + margin)
            wmask = masks[(size_t)row * 32 + lane];
        int mycnt = __popc(wmask);
        int pre = mycnt;
#pragma unroll
        for (int off = 1; off < 32; off <<= 1) {
            int t = __shfl_up(pre, off);
            if (lane >= off) pre += t;
        }
        const int total = __shfl(pre, 31);
        if (lane < 32) {
            int off = pre - mycnt;  // exclusive prefix (ascending k)
            unsigned int b = wmask;
            while (b) {
                int t = __ffs(b) - 1;
                if (off < 64) cand[off] = lane * 32 + t;
                ++off;
                b &= b - 1;
            }
        }
        __builtin_amdgcn_wave_barrier();

        float best = INFINITY;
        int bk = 0x7fffffff;
        if (total <= 64) {
            if (lane < total) {
                int k = cand[lane];
                const float4* er =
                    reinterpret_cast<const float4*>(&et[(size_t)k * DDIM]);
                const float4* xr4 = reinterpret_cast<const float4*>(xrow);
                float s = 0.f;
#pragma unroll 4
                for (int g2 = 0; g2 < 64; ++g2) {
                    float4 ev = er[g2];
                    float4 xv = xr4[g2];
                    s = fmaf(xv.x, ev.x, s);
                    s = fmaf(xv.y, ev.y, s);
                    s = fmaf(xv.z, ev.z, s);
                    s = fmaf(xv.w, ev.w, s);
                }
                float u = __fadd_rn(x2r, e2g[k]);
                best = __fsub_rn(u, __fmul_rn(2.0f, s));
                bk = k;
            }
        } else {
            // cold path (margin overflow — never expected): full 1024 rescan
#pragma unroll 1
            for (int c = 0; c < 16; ++c) {
                int k = lane + c * 64;
                const float4* er =
                    reinterpret_cast<const float4*>(&et[(size_t)k * DDIM]);
                const float4* xr4 = reinterpret_cast<const float4*>(xrow);
                float s = 0.f;
#pragma unroll 4
                for (int g2 = 0; g2 < 64; ++g2) {
                    float4 ev = er[g2];
                    float4 xv = xr4[g2];
                    s = fmaf(xv.x, ev.x, s);
                    s = fmaf(xv.y, ev.y, s);
                    s = fmaf(xv.z, ev.z, s);
                    s = fmaf(xv.w, ev.w, s);
                }
                float u = __fadd_rn(x2r, e2g[k]);
                float dct = __fsub_rn(u, __fmul_rn(2.0f, s));
                if (dct < best || (dct == best && k < bk)) {
                    best = dct;
                    bk = k;
                }
            }
        }
#pragma unroll
        for (int m = 1; m < 64; m <<= 1) {
            float od = __shfl_xor(best, m);
            int oi = __shfl_xor(bk, m);
            if (od < best || (od == best && oi < bk)) {
                best = od;
                bk = oi;
            }
        }
        if (lane == 0) idx[row] = bk & (KCODES - 1);
        __builtin_amdgcn_wave_barrier();  // LDS reuse across iterations
    }
}

// ---- output: gather + fp32 STE out + loss partial (verified) ---------------
__global__ __launch_bounds__(256) void vq_output(
    const float* __restrict__ x, const float* __restrict__ et,
    const int* __restrict__ idx, float* __restrict__ out,
    float* __restrict__ blockloss) {
    __shared__ int skb[64];
    __shared__ float red[256];
    const int rb = blockIdx.x;
    const int tid = threadIdx.x;
    if (tid < 64) skb[tid] = idx[rb * 64 + tid];
    __syncthreads();
    float lsum = 0.f;
    for (int r = 0; r < 64; ++r) {
        int row = rb * 64 + r;
        int k = skb[r];
        float xv = x[(size_t)row * DDIM + tid];
        float qv = et[(size_t)k * DDIM + tid];
        float diff = __fsub_rn(qv, xv);
        float qst = __fadd_rn(xv, diff);
        out[(size_t)row * DDIM + tid] = qst;
        lsum = fmaf(diff, diff, lsum);
    }
    red[tid] = lsum;
    __syncthreads();
    for (int s = 128; s > 0; s >>= 1) {
        if (tid < s) red[tid] += red[tid + s];
        __syncthreads();
    }
    if (tid == 0) blockloss[rb] = red[0];
}

// ---- deterministic loss reduce (verified) ----------------------------------
__global__ __launch_bounds__(512) void vq_loss_reduce(
    const float* __restrict__ blockloss, float* __restrict__ out_loss) {
    __shared__ float red[512];
    int tid = threadIdx.x;
    red[tid] = blockloss[tid];
    __syncthreads();
    for (int s = 256; s > 0; s >>= 1) {
        if (tid < s) red[tid] += red[tid + s];
        __syncthreads();
    }
    if (tid == 0) {
        float m = __fmul_rn(red[0], 1.0f / (float)((size_t)NROWS * DDIM));
        out_loss[0] = __fadd_rn(__fmul_rn(0.25f, m), m);
    }
}

extern "C" void kernel_launch(void* const* d_in, const int* in_sizes, int n_in,
                              void* d_out, int out_size, void* d_ws,
                              size_t ws_size, hipStream_t stream) {
    const float* x = (const float*)d_in[0];  // [32768, 256] fp32
    const float* e = (const float*)d_in[1];  // [256, 1024]  fp32
    float* out = (float*)d_out;              // 8388608 qst + 1 loss, fp32

    float* ws = (float*)d_ws;
    float* x2 = ws;                                    // 32768
    float* e2 = x2 + NROWS;                            // 1024
    float* et = e2 + KCODES;                           // 262144
    unsigned short* etb = (unsigned short*)(et + (size_t)KCODES * DDIM);
    unsigned short* xb = etb + (size_t)KCODES * DDIM;  // 8388608 u16
    unsigned int* masks = (unsigned int*)(xb + (size_t)NROWS * DDIM);
    float* bmin = (float*)(masks + (size_t)NROWS * 32);  // 32768*8
    int* idx = (int*)(bmin + (size_t)NROWS * 8);       // 32768
    int* counters = idx + NROWS;                       // 2 (+pad to 16B)
    unsigned long long* qlist =
        (unsigned long long*)(counters + 4);           // 32768 u64
    int* flist = (int*)(qlist + NROWS);                // 32768
    float* blockloss = (float*)(flist + NROWS);        // 512

    vq_front<<<X2BLK + E2BLK + 256, 256, 0, stream>>>(x, x2, xb, e, e2, et,
                                                      etb, counters);
    vq_screen<<<dim3(NROWS / 128, KCODES / 128), 256, 0, stream>>>(
        xb, etb, e2, x2, masks, bmin);
    vq_pick<<<NROWS / 256, 256, 0, stream>>>(masks, bmin, x2, idx, counters,
                                             qlist, flist);
    vq_rescan<<<QUICK_BLOCKS + FULL_BLOCKS, 256, 0, stream>>>(
        x, et, x2, e2, masks, bmin, counters, qlist, flist, idx);
    vq_output<<<NROWS / 64, 256, 0, stream>>>(x, et, idx, out, blockloss);
    vq_loss_reduce<<<1, 512, 0, stream>>>(blockloss, out + (size_t)NROWS * DDIM);
}